// Round 2
// baseline (1563.298 us; speedup 1.0000x reference)
//
#include <hip/hip_runtime.h>

typedef _Float16 f16;
typedef _Float16 f16x4 __attribute__((ext_vector_type(4)));
typedef _Float16 f16x8 __attribute__((ext_vector_type(8)));
typedef float    f32x4 __attribute__((ext_vector_type(4)));

constexpr int TT = 512;   // timesteps
constexpr int FF = 64;    // input features
constexpr int H1 = 128;   // layer-1 hidden (4*H1 = 512 gate cols)
constexpr int H2 = 64;    // layer-2 hidden (4*H2 = 256 gate cols)
constexpr int D1 = 25;    // dense-1 width
constexpr int AK = 264;   // LDS activation row stride in f16: 256 + 8 pad (4-bank skew)

__device__ __forceinline__ float sigm(float z) { return 1.f / (1.f + __expf(-z)); }

// One block = 16 batch rows (MFMA M=16), 4 waves. Weights register-stationary
// as MFMA B-fragments. LDS activation row per batch row: [x_t(64) | h1(128) | h2(64)]
// so L1 reads K=192 at cols 0..191 and L2 reads K=192 at cols 64..255 (h1 written once).
// Per step: 3 barriers; MFMA f32_16x16x32_f16, fp32 accum + gate math, f16 storage.
__global__ __launch_bounds__(256, 1)
void lstm_mfma(const float* __restrict__ x,  const float* __restrict__ W1,
               const float* __restrict__ U1, const float* __restrict__ b1,
               const float* __restrict__ W2, const float* __restrict__ U2,
               const float* __restrict__ b2, const float* __restrict__ Wd1,
               const float* __restrict__ bd1,const float* __restrict__ Wd2,
               const float* __restrict__ bd2, float* __restrict__ out)
{
    const int tid  = threadIdx.x;
    const int w    = tid >> 6;    // wave 0..3
    const int lane = tid & 63;
    const int quad = lane >> 4;   // 0..3
    const int lid  = lane & 15;   // 0..15
    const int b0   = blockIdx.x * 16;

    __shared__ __align__(16) f16 A_sh[16][AK];  // activation rows
    __shared__ float h2f[16][H2];
    __shared__ float dsh[16][D1];

    // ---- register-stationary weight B-fragments (lane: n = lane&15, k = quad*8+e) ----
    // L1: wave w owns gate cols {g*128 + 32w + 16h + lid}, tiles til = g*2+h (8 tiles)
    // L2: wave w owns gate cols {g*64 + 16w + lid}, tiles g (4 tiles)
    f16x8 wb1[8][6];
    f16x8 wb2[4][6];
    float bias1[8], bias2[4];
#pragma unroll
    for (int til = 0; til < 8; ++til) {
        const int g = til >> 1, h = til & 1;
        const int n = g * 128 + 32 * w + 16 * h + lid;
        bias1[til] = b1[n];
#pragma unroll
        for (int c = 0; c < 6; ++c) {
            f16x8 f;
#pragma unroll
            for (int e = 0; e < 8; ++e) {
                const int k = c * 32 + quad * 8 + e;           // 0..191
                const float v = (k < 64) ? W1[k * 512 + n] : U1[(k - 64) * 512 + n];
                f[e] = (f16)v;
            }
            wb1[til][c] = f;
        }
    }
#pragma unroll
    for (int g = 0; g < 4; ++g) {
        const int n = g * 64 + 16 * w + lid;
        bias2[g] = b2[n];
#pragma unroll
        for (int c = 0; c < 6; ++c) {
            f16x8 f;
#pragma unroll
            for (int e = 0; e < 8; ++e) {
                const int k = c * 32 + quad * 8 + e;           // 0..191 (A2-local)
                const float v = (k < 128) ? W2[k * 256 + n] : U2[(k - 128) * 256 + n];
                f[e] = (f16)v;
            }
            wb2[g][c] = f;
        }
    }

    float c1s[8] = {0.f, 0.f, 0.f, 0.f, 0.f, 0.f, 0.f, 0.f};
    float c2s[4] = {0.f, 0.f, 0.f, 0.f};

    // zero activation rows, then stage x[t=0]
    for (int i = tid; i < 16 * AK / 2; i += 256) ((unsigned*)A_sh)[i] = 0u;
    __syncthreads();
    {
        const int br = tid >> 4, cq = tid & 15;
        const float4 xv = *(const float4*)&x[((size_t)(b0 + br) * TT + 0) * FF + cq * 4];
        f16x4 p; p[0] = (f16)xv.x; p[1] = (f16)xv.y; p[2] = (f16)xv.z; p[3] = (f16)xv.w;
        *(f16x4*)&A_sh[br][cq * 4] = p;
    }
    __syncthreads();

    for (int t = 0; t < TT; ++t) {
        // ---- S1: A-fragment reads (x_t | h1[t-1]) for L1, h2[t-1] chunks for L2 ----
        f16x8 af[6], ah2a, ah2b;
#pragma unroll
        for (int c = 0; c < 6; ++c)
            af[c] = *(const f16x8*)&A_sh[lid][c * 32 + quad * 8];
        ah2a = *(const f16x8*)&A_sh[lid][192 + quad * 8];
        ah2b = *(const f16x8*)&A_sh[lid][224 + quad * 8];
        __syncthreads();                                     // S2: reads done before writes

        // prefetch x[t+1] (global latency hidden under L1 MFMA+gates; drains at S4)
        float4 xv;
        const bool havex = (t + 1 < TT);
        if (havex)
            xv = *(const float4*)&x[((size_t)(b0 + (tid >> 4)) * TT + (t + 1)) * FF + (tid & 15) * 4];

        // ---- S3: layer-1 MFMA (8 N-tiles x 6 K-chunks) + gates ----
        f32x4 acc[8];
#pragma unroll
        for (int til = 0; til < 8; ++til) {
            f32x4 a = {0.f, 0.f, 0.f, 0.f};
#pragma unroll
            for (int c = 0; c < 6; ++c)
                a = __builtin_amdgcn_mfma_f32_16x16x32_f16(af[c], wb1[til][c], a, 0, 0, 0);
            acc[til] = a;
        }
#pragma unroll
        for (int h = 0; h < 2; ++h) {
#pragma unroll
            for (int r = 0; r < 4; ++r) {
                // D layout: row m = quad*4 + r (batch), col n = lid. Gates i,f,g,o = tiles h,2+h,4+h,6+h.
                const float zi = acc[0 + h][r] + bias1[0 + h];
                const float zf = acc[2 + h][r] + bias1[2 + h];
                const float zg = acc[4 + h][r] + bias1[4 + h];
                const float zo = acc[6 + h][r] + bias1[6 + h];
                const float ig = sigm(zi), fg = sigm(zf);
                const float gg = fmaxf(zg, 0.f), og = sigm(zo);
                const float cc = fg * c1s[h * 4 + r] + ig * gg;
                c1s[h * 4 + r] = cc;
                const float hv = og * fmaxf(cc, 0.f);
                A_sh[quad * 4 + r][64 + 32 * w + 16 * h + lid] = (f16)hv;
            }
        }
        __syncthreads();                                     // S4: h1[t] visible

        // ---- S5: layer-2 MFMA (4 N-tiles x 6 K-chunks) + gates, stage x[t+1] ----
        f16x8 a2[6];
#pragma unroll
        for (int c = 0; c < 4; ++c)
            a2[c] = *(const f16x8*)&A_sh[lid][64 + c * 32 + quad * 8];
        a2[4] = ah2a; a2[5] = ah2b;
        f32x4 acc2[4];
#pragma unroll
        for (int g = 0; g < 4; ++g) {
            f32x4 a = {0.f, 0.f, 0.f, 0.f};
#pragma unroll
            for (int c = 0; c < 6; ++c)
                a = __builtin_amdgcn_mfma_f32_16x16x32_f16(a2[c], wb2[g][c], a, 0, 0, 0);
            acc2[g] = a;
        }
#pragma unroll
        for (int r = 0; r < 4; ++r) {
            const float zi = acc2[0][r] + bias2[0];
            const float zf = acc2[1][r] + bias2[1];
            const float zg = acc2[2][r] + bias2[2];
            const float zo = acc2[3][r] + bias2[3];
            const float ig = sigm(zi), fg = sigm(zf);
            const float gg = fmaxf(zg, 0.f), og = sigm(zo);
            const float cc = fg * c2s[r] + ig * gg;
            c2s[r] = cc;
            const float hv = og * fmaxf(cc, 0.f);
            A_sh[quad * 4 + r][192 + 16 * w + lid] = (f16)hv;
            if (t == TT - 1) h2f[quad * 4 + r][16 * w + lid] = hv;
        }
        if (havex) {
            f16x4 p; p[0] = (f16)xv.x; p[1] = (f16)xv.y; p[2] = (f16)xv.z; p[3] = (f16)xv.w;
            *(f16x4*)&A_sh[tid >> 4][(tid & 15) * 4] = p;
        }
        __syncthreads();                                     // S6: h2[t], x[t+1] visible
    }

    // ---- dense head: out[b] = (h2 @ Wd1 + bd1) @ Wd2 + bd2 ----
    for (int idx = tid; idx < 16 * D1; idx += 256) {
        const int bq = idx / D1, p = idx % D1;
        float d = bd1[p];
#pragma unroll
        for (int k = 0; k < H2; ++k) d += h2f[bq][k] * Wd1[k * D1 + p];
        dsh[bq][p] = d * Wd2[p];
    }
    __syncthreads();
    if (tid < 16) {
        float o = bd2[0];
#pragma unroll
        for (int p = 0; p < D1; ++p) o += dsh[tid][p];
        out[b0 + tid] = o;
    }
}

extern "C" void kernel_launch(void* const* d_in, const int* in_sizes, int n_in,
                              void* d_out, int out_size, void* d_ws, size_t ws_size,
                              hipStream_t stream) {
    (void)in_sizes; (void)n_in; (void)out_size; (void)d_ws; (void)ws_size;
    const float* x   = (const float*)d_in[0];
    const float* W1  = (const float*)d_in[1];
    const float* U1  = (const float*)d_in[2];
    const float* b1  = (const float*)d_in[3];
    const float* W2  = (const float*)d_in[4];
    const float* U2  = (const float*)d_in[5];
    const float* b2  = (const float*)d_in[6];
    const float* Wd1 = (const float*)d_in[7];
    const float* bd1 = (const float*)d_in[8];
    const float* Wd2 = (const float*)d_in[9];
    const float* bd2 = (const float*)d_in[10];
    float* out = (float*)d_out;

    lstm_mfma<<<dim3(32), dim3(256), 0, stream>>>(
        x, W1, U1, b1, W2, U2, b2, Wd1, bd1, Wd2, bd2, out);
}